// Round 1
// baseline (405.249 us; speedup 1.0000x reference)
//
#include <hip/hip_runtime.h>

// ---------------------------------------------------------------------------
// LoRA forward: out = x @ W^T + 2 * (x @ A^T) @ B^T
//   x:[4,4096,2048] f32, W:[2048,2048] f32, A:[16,2048] f32, B:[2048,16] f32
// R4 strategy:
//   1) Xb   = bf16(x)
//   2) W_eff= bf16(W + 2 * B @ A)
//   3) out  = Xb @ W_eff^T  -- 256x256 8-phase schedule (T2+T3+T4+T5):
//      8 waves (2Mx4N), BK=64, double-buffered 128 KiB LDS, counted
//      s_waitcnt vmcnt(8) at every phase end (never 0 in the loop),
//      raw s_barrier, s_setprio(1) around each 16-MFMA cluster.
//      Staging keeps the proven (seg+row)&7 XOR swizzle -> 0 bank conflicts
//      with global_load_lds width=16 (linear LDS dest, pre-swizzled source).
// Phase map (iteration computes tiles t=2it [buf0] and t+1 [buf1]):
//   ph1 P1(0,0)|stage A(t+1)hm1   ph5 P1(0,0)|stage A(t+2)hm1
//   ph2 P2(1,0)|stage B(t+1)hn1   ph6 P2(1,0)|stage B(t+2)hn1
//   ph3 P3(0,1)|stage B(t+2)hn0   ph7 P3(0,1)|stage B(t+3)hn0
//   ph4 P4(1,1)|stage A(t+2)hm0   ph8 P4(1,1)|stage A(t+3)hm0
// Every stage lands after the previous tile's last read of that slab
// (quadrant read-sets are slab-aligned: A rounds {hm,hm+2} read only in
// hm-phases; B staged wave-split so 32-row hn-slabs read only in hn-phases).
// vmcnt(8) = 4 phases x 2 loads margin covers every consumer exactly.
// Tail: stage tiles clamped to NT-1 (never skipped) so counting stays exact.
// ---------------------------------------------------------------------------

typedef __bf16 bf16x8 __attribute__((ext_vector_type(8)));
typedef float  f32x4  __attribute__((ext_vector_type(4)));
typedef unsigned short u16x8 __attribute__((ext_vector_type(8)));

#define AS1C(p) ((const __attribute__((address_space(1))) void*)(p))
#define AS3(p)  ((__attribute__((address_space(3))) void*)(p))

__device__ __forceinline__ unsigned short f2bf_rne(float f) {
  unsigned int u = __float_as_uint(f);
  u += 0x7FFFu + ((u >> 16) & 1u);
  return (unsigned short)(u >> 16);
}

constexpr int M_ = 16384;   // 4 * 4096
constexpr int N_ = 2048;    // D_out
constexpr int K_ = 2048;    // D_in
constexpr int R_ = 16;
constexpr float SCALING = 2.0f;  // 32/16

constexpr int BM = 256, BN = 256, BK = 64;
constexpr int NT = K_ / BK;      // 32 k-tiles, 16 loop iterations

// ---- kernel 1: x f32 -> bf16, 8 elems/thread --------------------------------
__global__ __launch_bounds__(256) void cvt_kernel(const float* __restrict__ in,
                                                  unsigned short* __restrict__ out) {
  size_t i = (size_t)blockIdx.x * blockDim.x + threadIdx.x;
  const float4* p = (const float4*)in;
  float4 a = p[2 * i];
  float4 b = p[2 * i + 1];
  u16x8 o;
  o[0] = f2bf_rne(a.x); o[1] = f2bf_rne(a.y); o[2] = f2bf_rne(a.z); o[3] = f2bf_rne(a.w);
  o[4] = f2bf_rne(b.x); o[5] = f2bf_rne(b.y); o[6] = f2bf_rne(b.z); o[7] = f2bf_rne(b.w);
  ((u16x8*)out)[i] = o;
}

// ---- kernel 2: W_eff = bf16(W + 2 * B @ A), [N,K] row-major -----------------
__global__ __launch_bounds__(256) void weff_kernel(const float* __restrict__ W,
                                                   const float* __restrict__ A,
                                                   const float* __restrict__ Bl,
                                                   unsigned short* __restrict__ out) {
  int idx = blockIdx.x * blockDim.x + threadIdx.x;  // over N_*K_
  int o = idx >> 11;        // / 2048
  int d = idx & 2047;       // % 2048
  float acc = W[idx];
#pragma unroll
  for (int r = 0; r < R_; ++r)
    acc = fmaf(SCALING * Bl[o * R_ + r], A[r * K_ + d], acc);
  out[idx] = f2bf_rne(acc);
}

// ---- kernel 3: C[M,N] = Xb[M,K] @ W_eff[N,K]^T  (bf16 in, f32 out) ----------
__global__ __launch_bounds__(512, 2) void gemm_kernel(const unsigned short* __restrict__ X,
                                                      const unsigned short* __restrict__ W,
                                                      float* __restrict__ C) {
  __shared__ __align__(16) unsigned short sA[2][BM * BK];  // 2 x 32 KB
  __shared__ __align__(16) unsigned short sB[2][BN * BK];  // 2 x 32 KB

  const int tid  = threadIdx.x;
  const int w    = tid >> 6;
  const int lane = tid & 63;
  const int fm   = lane & 15;
  const int quad = lane >> 4;

  // XCD-aware swizzle: 512 blocks, 8 XCDs, each XCD gets 8 bm-rows x 8 bn-cols.
  const int id = blockIdx.x;
  const int bm = ((id & 7) * 8 + (id >> 6)) * BM;  // (xcd*8 + slot/8) * 256
  const int bn = ((id >> 3) & 7) * BN;             // (slot%8) * 256

  const int wrow = (w >> 2) * 128;  // wave's row offset in 256-row tile
  const int wcol = (w & 3) * 64;    // wave's col offset

  // --- staging addressing -------------------------------------------------
  // A rounds: 64 contiguous rows; thread covers row (tid>>3), 16B-seg (tid&7)
  // physical; it fetches logical seg gseg so LDS phys seg = (g + row) & 7.
  const int strow = tid >> 3;                  // 0..63
  const int gseg  = ((tid & 7) - strow) & 7;
  // B stages wave-split over 32-row hn-slabs: waves 0-3 -> slab 4p+hn,
  // waves 4-7 -> slab 4p+hn+2.  Global row base (identity LDS layout):
  const int brow0 = 64 * (tid >> 8) + (strow & 31);

  const unsigned short* xa = X + (size_t)(bm + strow) * K_ + gseg * 8;
  const unsigned short* xb = W + (size_t)(bn + brow0) * K_ + gseg * 8;

  // wave-uniform LDS staging bases (elements); HW adds lane*16B.
  const int aw = w * 8 * BK;                               // A: + (hm*64+128c)*BK
  const int bw = ((w >> 2) * 64 + (w & 3) * 8) * BK;       // B: + (128p+32hn)*BK

  // fragment k-offsets: phys seg = (t*4 + quad + fm) & 7  (row = ... + fm)
  const int sp0 = ((quad + fm) & 7) * 8;
  const int sp1 = ((quad + fm + 4) & 7) * 8;

  f32x4 acc[8][4] = {};

#define STAGE_A(hm, kt, b) do {                                                   \
    __builtin_amdgcn_global_load_lds(AS1C(xa + (size_t)((hm) * 64) * K_ + (kt) * BK), \
        AS3(&sA[b][((hm) * 64) * BK + aw]), 16, 0, 0);                            \
    __builtin_amdgcn_global_load_lds(AS1C(xa + (size_t)((hm) * 64 + 128) * K_ + (kt) * BK), \
        AS3(&sA[b][((hm) * 64 + 128) * BK + aw]), 16, 0, 0);                      \
  } while (0)

#define STAGE_B(hn, kt, b) do {                                                   \
    __builtin_amdgcn_global_load_lds(AS1C(xb + (size_t)((hn) * 32) * K_ + (kt) * BK), \
        AS3(&sB[b][((hn) * 32) * BK + bw]), 16, 0, 0);                            \
    __builtin_amdgcn_global_load_lds(AS1C(xb + (size_t)((hn) * 32 + 128) * K_ + (kt) * BK), \
        AS3(&sB[b][((hn) * 32 + 128) * BK + bw]), 16, 0, 0);                      \
  } while (0)

  // phase: 12 ds_read_b128 || stage 1 slab-group -> barrier -> lgkmcnt(0) ->
  //        prio(1) 16 MFMA prio(0) -> vmcnt(8) -> barrier
#define PHASE(tb, hm, hn, STAGE) do {                                             \
    bf16x8 af[4][2], bv[2][2];                                                    \
    _Pragma("unroll")                                                             \
    for (int i2 = 0; i2 < 4; ++i2) {                                              \
      const int ra = (wrow + (hm) * 64 + i2 * 16 + fm) * BK;                      \
      af[i2][0] = *(const bf16x8*)&sA[tb][ra + sp0];                              \
      af[i2][1] = *(const bf16x8*)&sA[tb][ra + sp1];                              \
    }                                                                             \
    _Pragma("unroll")                                                             \
    for (int j2 = 0; j2 < 2; ++j2) {                                              \
      const int rb = (wcol + (hn) * 32 + j2 * 16 + fm) * BK;                      \
      bv[j2][0] = *(const bf16x8*)&sB[tb][rb + sp0];                              \
      bv[j2][1] = *(const bf16x8*)&sB[tb][rb + sp1];                              \
    }                                                                             \
    STAGE;                                                                        \
    __builtin_amdgcn_s_barrier();                                                 \
    asm volatile("s_waitcnt lgkmcnt(0)" ::: "memory");                            \
    __builtin_amdgcn_s_setprio(1);                                                \
    _Pragma("unroll")                                                             \
    for (int i2 = 0; i2 < 4; ++i2)                                                \
      _Pragma("unroll")                                                           \
      for (int j2 = 0; j2 < 2; ++j2) {                                            \
        acc[(hm) * 4 + i2][(hn) * 2 + j2] = __builtin_amdgcn_mfma_f32_16x16x32_bf16( \
            af[i2][0], bv[j2][0], acc[(hm) * 4 + i2][(hn) * 2 + j2], 0, 0, 0);    \
        acc[(hm) * 4 + i2][(hn) * 2 + j2] = __builtin_amdgcn_mfma_f32_16x16x32_bf16( \
            af[i2][1], bv[j2][1], acc[(hm) * 4 + i2][(hn) * 2 + j2], 0, 0, 0);    \
      }                                                                           \
    __builtin_amdgcn_s_setprio(0);                                                \
    asm volatile("s_waitcnt vmcnt(8)" ::: "memory");                              \
    __builtin_amdgcn_s_barrier();                                                 \
  } while (0)

  // prologue: tile0 fully + tile1 {B hn0, A hm0}; oldest-first matches loop ages
  STAGE_B(0, 0, 0);
  STAGE_A(0, 0, 0);
  STAGE_A(1, 0, 0);
  STAGE_B(1, 0, 0);
  STAGE_B(0, 1, 1);
  STAGE_A(0, 1, 1);
  asm volatile("s_waitcnt vmcnt(8)" ::: "memory");  // drains tile0 {B hn0, A hm0}
  __builtin_amdgcn_s_barrier();

#pragma unroll 1
  for (int it = 0; it < NT / 2; ++it) {
    const int t1 = 2 * it + 1;                              // always < NT
    const int t2 = (2 * it + 2 < NT) ? 2 * it + 2 : NT - 1; // clamped, never skipped
    const int t3 = (2 * it + 3 < NT) ? 2 * it + 3 : NT - 1;
    PHASE(0, 0, 0, STAGE_A(1, t1, 1));
    PHASE(0, 1, 0, STAGE_B(1, t1, 1));
    PHASE(0, 0, 1, STAGE_B(0, t2, 0));
    PHASE(0, 1, 1, STAGE_A(0, t2, 0));
    PHASE(1, 0, 0, STAGE_A(1, t2, 0));
    PHASE(1, 1, 0, STAGE_B(1, t2, 0));
    PHASE(1, 0, 1, STAGE_B(0, t3, 1));
    PHASE(1, 1, 1, STAGE_A(0, t3, 1));
  }

  // drain in-flight LDS-writes before this workgroup's LDS can be reassigned
  asm volatile("s_waitcnt vmcnt(0)" ::: "memory");

  // epilogue: C/D layout col = lane&15, row = (lane>>4)*4 + r. Nontemporal:
  // C is never re-read; keep it out of L2/L3 so X/W stay resident.
  const int r0 = quad * 4;
#pragma unroll
  for (int i = 0; i < 8; ++i) {
#pragma unroll
    for (int j = 0; j < 4; ++j) {
      size_t base = (size_t)(bm + wrow + i * 16 + r0) * N_ + (size_t)(bn + wcol + j * 16 + fm);
#pragma unroll
      for (int r = 0; r < 4; ++r)
        __builtin_nontemporal_store(acc[i][j][r], &C[base + (size_t)r * N_]);
    }
  }
#undef PHASE
#undef STAGE_A
#undef STAGE_B
}

extern "C" void kernel_launch(void* const* d_in, const int* in_sizes, int n_in,
                              void* d_out, int out_size, void* d_ws, size_t ws_size,
                              hipStream_t stream) {
  const float* x  = (const float*)d_in[0];  // [4,4096,2048]
  const float* W  = (const float*)d_in[1];  // [2048,2048]
  const float* A  = (const float*)d_in[2];  // [16,2048]
  const float* Bl = (const float*)d_in[3];  // [2048,16]
  float* out = (float*)d_out;               // [4,4096,2048] f32

  // workspace: Xb (M*K bf16 = 64 MB) | W_eff (N*K bf16 = 8 MB)
  unsigned short* Xb   = (unsigned short*)d_ws;
  unsigned short* Weff = Xb + (size_t)M_ * K_;

  cvt_kernel<<<(int)((size_t)M_ * K_ / 8 / 256), 256, 0, stream>>>(x, Xb);
  weff_kernel<<<(N_ * K_) / 256, 256, 0, stream>>>(W, A, Bl, Weff);

  gemm_kernel<<<(M_ / BM) * (N_ / BN), 512, 0, stream>>>(Xb, Weff, out);
}

// Round 2
// 403.688 us; speedup vs baseline: 1.0039x; 1.0039x over previous
//
#include <hip/hip_runtime.h>

// ---------------------------------------------------------------------------
// LoRA forward: out = x @ W^T + 2 * (x @ A^T) @ B^T
//   x:[4,4096,2048] f32, W:[2048,2048] f32, A:[16,2048] f32, B:[2048,16] f32
// R5: 256x256 8-phase schedule, vmcnt counted ONLY at phases 4 and 8 (the R4
// regression was per-phase vmcnt(8): 8 just-in-time convoy points/iter ->
// latency-serialized. Now: 2 waits/iter, vmcnt(4), 2-5 phase slack per load).
// MFMA order restored to k-step-outer (8 independent MFMAs between dependent
// same-acc pairs). Everything else unchanged from R4:
//   8 waves (2Mx4N), BK=64, double-buffered 128 KiB LDS, raw s_barrier,
//   s_setprio(1) around MFMA clusters, (seg+row)&7 XOR staging swizzle
//   (0 bank conflicts, linear LDS dest for global_load_lds width=16).
// Phase map (iteration computes tiles t=2it [buf0] and t+1 [buf1]):
//   ph1 P(0,0)b0|stage A(t+1)hm1   ph5 P(0,0)b1|stage A(t+2)hm1
//   ph2 P(1,0)b0|stage B(t+1)hn1   ph6 P(1,0)b1|stage B(t+2)hn1
//   ph3 P(0,1)b0|stage B(t+2)hn0   ph7 P(0,1)b1|stage B(t+3)hn0
//   ph4 P(1,1)b0|stage A(t+2)hm0 +vmcnt(4)
//                                  ph8 P(1,1)b1|stage A(t+3)hm0 +vmcnt(4)
// Drain check (steady state, 2 vm-instr per stage):
//   ph4-end in flight {prev7,prev8,ph1..4}=12 -> vmcnt(4) drains prev7,prev8
//   (read ph5), ph1 (read ph6), ph2 (read ph7).  ph8-end in flight
//   {ph3..8}=12 -> drains ph3,ph4 (read next ph1), ph5 (next ph2), ph6
//   (next ph3); leaves ph7,ph8 (read next ph5, drained next ph4-end).
// Tail: stage tiles clamped to NT-1 (never skipped) so counting stays exact.
// ---------------------------------------------------------------------------

typedef __bf16 bf16x8 __attribute__((ext_vector_type(8)));
typedef float  f32x4  __attribute__((ext_vector_type(4)));
typedef unsigned short u16x8 __attribute__((ext_vector_type(8)));

#define AS1C(p) ((const __attribute__((address_space(1))) void*)(p))
#define AS3(p)  ((__attribute__((address_space(3))) void*)(p))

__device__ __forceinline__ unsigned short f2bf_rne(float f) {
  unsigned int u = __float_as_uint(f);
  u += 0x7FFFu + ((u >> 16) & 1u);
  return (unsigned short)(u >> 16);
}

constexpr int M_ = 16384;   // 4 * 4096
constexpr int N_ = 2048;    // D_out
constexpr int K_ = 2048;    // D_in
constexpr int R_ = 16;
constexpr float SCALING = 2.0f;  // 32/16

constexpr int BM = 256, BN = 256, BK = 64;
constexpr int NT = K_ / BK;      // 32 k-tiles, 16 loop iterations

// ---- kernel 1: x f32 -> bf16, 8 elems/thread --------------------------------
__global__ __launch_bounds__(256) void cvt_kernel(const float* __restrict__ in,
                                                  unsigned short* __restrict__ out) {
  size_t i = (size_t)blockIdx.x * blockDim.x + threadIdx.x;
  const float4* p = (const float4*)in;
  float4 a = p[2 * i];
  float4 b = p[2 * i + 1];
  u16x8 o;
  o[0] = f2bf_rne(a.x); o[1] = f2bf_rne(a.y); o[2] = f2bf_rne(a.z); o[3] = f2bf_rne(a.w);
  o[4] = f2bf_rne(b.x); o[5] = f2bf_rne(b.y); o[6] = f2bf_rne(b.z); o[7] = f2bf_rne(b.w);
  ((u16x8*)out)[i] = o;
}

// ---- kernel 2: W_eff = bf16(W + 2 * B @ A), [N,K] row-major -----------------
__global__ __launch_bounds__(256) void weff_kernel(const float* __restrict__ W,
                                                   const float* __restrict__ A,
                                                   const float* __restrict__ Bl,
                                                   unsigned short* __restrict__ out) {
  int idx = blockIdx.x * blockDim.x + threadIdx.x;  // over N_*K_
  int o = idx >> 11;        // / 2048
  int d = idx & 2047;       // % 2048
  float acc = W[idx];
#pragma unroll
  for (int r = 0; r < R_; ++r)
    acc = fmaf(SCALING * Bl[o * R_ + r], A[r * K_ + d], acc);
  out[idx] = f2bf_rne(acc);
}

// ---- kernel 3: C[M,N] = Xb[M,K] @ W_eff[N,K]^T  (bf16 in, f32 out) ----------
__global__ __launch_bounds__(512, 2) void gemm_kernel(const unsigned short* __restrict__ X,
                                                      const unsigned short* __restrict__ W,
                                                      float* __restrict__ C) {
  __shared__ __align__(16) unsigned short sA[2][BM * BK];  // 2 x 32 KB
  __shared__ __align__(16) unsigned short sB[2][BN * BK];  // 2 x 32 KB

  const int tid  = threadIdx.x;
  const int w    = tid >> 6;
  const int lane = tid & 63;
  const int fm   = lane & 15;
  const int quad = lane >> 4;

  // XCD-aware swizzle: 512 blocks, 8 XCDs, each XCD gets 8 bm-rows x 8 bn-cols.
  const int id = blockIdx.x;
  const int bm = ((id & 7) * 8 + (id >> 6)) * BM;  // (xcd*8 + slot/8) * 256
  const int bn = ((id >> 3) & 7) * BN;             // (slot%8) * 256

  const int wrow = (w >> 2) * 128;  // wave's row offset in 256-row tile
  const int wcol = (w & 3) * 64;    // wave's col offset

  // --- staging addressing -------------------------------------------------
  // A rounds: 64 contiguous rows; thread covers row (tid>>3), 16B-seg (tid&7)
  // physical; it fetches logical seg gseg so LDS phys seg = (g + row) & 7.
  const int strow = tid >> 3;                  // 0..63
  const int gseg  = ((tid & 7) - strow) & 7;
  // B stages wave-split over 32-row hn-slabs: waves 0-3 -> slab 4p+hn,
  // waves 4-7 -> slab 4p+hn+2.  Global row base (identity LDS layout):
  const int brow0 = 64 * (tid >> 8) + (strow & 31);

  const unsigned short* xa = X + (size_t)(bm + strow) * K_ + gseg * 8;
  const unsigned short* xb = W + (size_t)(bn + brow0) * K_ + gseg * 8;

  // wave-uniform LDS staging bases (elements); HW adds lane*16B.
  const int aw = w * 8 * BK;                               // A: + (hm*64+128c)*BK
  const int bw = ((w >> 2) * 64 + (w & 3) * 8) * BK;       // B: + (128p+32hn)*BK

  // fragment k-offsets: phys seg = (t*4 + quad + fm) & 7  (row = ... + fm)
  const int sp0 = ((quad + fm) & 7) * 8;
  const int sp1 = ((quad + fm + 4) & 7) * 8;

  f32x4 acc[8][4] = {};

#define STAGE_A(hm, kt, b) do {                                                   \
    __builtin_amdgcn_global_load_lds(AS1C(xa + (size_t)((hm) * 64) * K_ + (kt) * BK), \
        AS3(&sA[b][((hm) * 64) * BK + aw]), 16, 0, 0);                            \
    __builtin_amdgcn_global_load_lds(AS1C(xa + (size_t)((hm) * 64 + 128) * K_ + (kt) * BK), \
        AS3(&sA[b][((hm) * 64 + 128) * BK + aw]), 16, 0, 0);                      \
  } while (0)

#define STAGE_B(hn, kt, b) do {                                                   \
    __builtin_amdgcn_global_load_lds(AS1C(xb + (size_t)((hn) * 32) * K_ + (kt) * BK), \
        AS3(&sB[b][((hn) * 32) * BK + bw]), 16, 0, 0);                            \
    __builtin_amdgcn_global_load_lds(AS1C(xb + (size_t)((hn) * 32 + 128) * K_ + (kt) * BK), \
        AS3(&sB[b][((hn) * 32 + 128) * BK + bw]), 16, 0, 0);                      \
  } while (0)

#define VMC4 asm volatile("s_waitcnt vmcnt(4)" ::: "memory")
#define NOVM (void)0

  // phase: 12 ds_read_b128 || stage 1 slab-group -> barrier -> lgkmcnt(0) ->
  //        prio(1) 16 MFMA (k-step outer: 8 independent per step) prio(0) ->
  //        [vmcnt(4) at ph4/ph8 only] -> barrier
#define PHASE(tb, hm, hn, STAGE, VMW) do {                                        \
    bf16x8 af[4][2], bv[2][2];                                                    \
    _Pragma("unroll")                                                             \
    for (int i2 = 0; i2 < 4; ++i2) {                                              \
      const int ra = (wrow + (hm) * 64 + i2 * 16 + fm) * BK;                      \
      af[i2][0] = *(const bf16x8*)&sA[tb][ra + sp0];                              \
      af[i2][1] = *(const bf16x8*)&sA[tb][ra + sp1];                              \
    }                                                                             \
    _Pragma("unroll")                                                             \
    for (int j2 = 0; j2 < 2; ++j2) {                                              \
      const int rb = (wcol + (hn) * 32 + j2 * 16 + fm) * BK;                      \
      bv[j2][0] = *(const bf16x8*)&sB[tb][rb + sp0];                              \
      bv[j2][1] = *(const bf16x8*)&sB[tb][rb + sp1];                              \
    }                                                                             \
    STAGE;                                                                        \
    __builtin_amdgcn_s_barrier();                                                 \
    asm volatile("s_waitcnt lgkmcnt(0)" ::: "memory");                            \
    __builtin_amdgcn_s_setprio(1);                                                \
    _Pragma("unroll")                                                             \
    for (int ks = 0; ks < 2; ++ks)                                                \
      _Pragma("unroll")                                                           \
      for (int i2 = 0; i2 < 4; ++i2)                                              \
        _Pragma("unroll")                                                         \
        for (int j2 = 0; j2 < 2; ++j2)                                            \
          acc[(hm) * 4 + i2][(hn) * 2 + j2] = __builtin_amdgcn_mfma_f32_16x16x32_bf16( \
              af[i2][ks], bv[j2][ks], acc[(hm) * 4 + i2][(hn) * 2 + j2], 0, 0, 0); \
    __builtin_amdgcn_s_setprio(0);                                                \
    VMW;                                                                          \
    __builtin_amdgcn_s_barrier();                                                 \
  } while (0)

  // prologue: tile0 fully + tile1 {B hn0, A hm0}; vmcnt(4) drains tile0,
  // leaves the 2 tile1 stage-calls (4 vm-instr) in flight.
  STAGE_B(0, 0, 0);
  STAGE_A(0, 0, 0);
  STAGE_A(1, 0, 0);
  STAGE_B(1, 0, 0);
  STAGE_B(0, 1, 1);
  STAGE_A(0, 1, 1);
  asm volatile("s_waitcnt vmcnt(4)" ::: "memory");
  __builtin_amdgcn_s_barrier();

#pragma unroll 1
  for (int it = 0; it < NT / 2; ++it) {
    const int t1 = 2 * it + 1;                              // always < NT
    const int t2 = (2 * it + 2 < NT) ? 2 * it + 2 : NT - 1; // clamped, never skipped
    const int t3 = (2 * it + 3 < NT) ? 2 * it + 3 : NT - 1;
    PHASE(0, 0, 0, STAGE_A(1, t1, 1), NOVM);
    PHASE(0, 1, 0, STAGE_B(1, t1, 1), NOVM);
    PHASE(0, 0, 1, STAGE_B(0, t2, 0), NOVM);
    PHASE(0, 1, 1, STAGE_A(0, t2, 0), VMC4);
    PHASE(1, 0, 0, STAGE_A(1, t2, 0), NOVM);
    PHASE(1, 1, 0, STAGE_B(1, t2, 0), NOVM);
    PHASE(1, 0, 1, STAGE_B(0, t3, 1), NOVM);
    PHASE(1, 1, 1, STAGE_A(0, t3, 1), VMC4);
  }

  // drain in-flight LDS-writes before this workgroup's LDS can be reassigned
  asm volatile("s_waitcnt vmcnt(0)" ::: "memory");

  // epilogue: C/D layout col = lane&15, row = (lane>>4)*4 + r. Nontemporal:
  // C is never re-read; keep it out of L2/L3 so X/W stay resident.
  const int r0 = quad * 4;
#pragma unroll
  for (int i = 0; i < 8; ++i) {
#pragma unroll
    for (int j = 0; j < 4; ++j) {
      size_t base = (size_t)(bm + wrow + i * 16 + r0) * N_ + (size_t)(bn + wcol + j * 16 + fm);
#pragma unroll
      for (int r = 0; r < 4; ++r)
        __builtin_nontemporal_store(acc[i][j][r], &C[base + (size_t)r * N_]);
    }
  }
#undef PHASE
#undef STAGE_A
#undef STAGE_B
#undef VMC4
#undef NOVM
}

extern "C" void kernel_launch(void* const* d_in, const int* in_sizes, int n_in,
                              void* d_out, int out_size, void* d_ws, size_t ws_size,
                              hipStream_t stream) {
  const float* x  = (const float*)d_in[0];  // [4,4096,2048]
  const float* W  = (const float*)d_in[1];  // [2048,2048]
  const float* A  = (const float*)d_in[2];  // [16,2048]
  const float* Bl = (const float*)d_in[3];  // [2048,16]
  float* out = (float*)d_out;               // [4,4096,2048] f32

  // workspace: Xb (M*K bf16 = 64 MB) | W_eff (N*K bf16 = 8 MB)
  unsigned short* Xb   = (unsigned short*)d_ws;
  unsigned short* Weff = Xb + (size_t)M_ * K_;

  cvt_kernel<<<(int)((size_t)M_ * K_ / 8 / 256), 256, 0, stream>>>(x, Xb);
  weff_kernel<<<(N_ * K_) / 256, 256, 0, stream>>>(W, A, Bl, Weff);

  gemm_kernel<<<(M_ / BM) * (N_ / BN), 512, 0, stream>>>(Xb, Weff, out);
}

// Round 3
// 379.902 us; speedup vs baseline: 1.0667x; 1.0626x over previous
//
#include <hip/hip_runtime.h>

// ---------------------------------------------------------------------------
// LoRA forward: out = x @ W^T + 2 * (x @ A^T) @ B^T
// R6: fix the LDS-read-bandwidth bottleneck found in R5's post-mortem.
//   R5 reloaded both operands' fragments every phase: 48 ds_read_b128 /wave
//   /K-tile vs minimal 24 -> 457 KB LDS traffic/K-tile > MFMA time -> 32%
//   MfmaUtil. R6 snakes the quadrant order (0,0)->(0,1)->(1,1)->(1,0) and
//   keeps fragments in registers: af (one hm set), bv0+bv1 (both hn sets).
//   ds_reads/K-tile: ph1=12, ph2=4, ph3=8, ph4=0  (24 total, minimal).
// Stage map (1 slab-group = 2 global_load_lds per phase; it computes
// t=2it in buf0, t+1 in buf1):
//   ph1 (0,0)b0 rd A0,B0 | stage A1 b1 t+1     ph5 (0,0)b1 rd A0,B0 | A1 b0 t+2
//   ph2 (0,1)b0 rd B1    | stage A0 b0 t+2     ph6 (0,1)b1 rd B1    | A0 b1 t+3
//   ph3 (1,1)b0 rd A1    | stage B0 b0 t+2     ph7 (1,1)b1 rd A1    | B0 b1 t+3
//   ph4 (1,0)b0 rd --    | stage B1 b0 t+2     ph8 (1,0)b1 rd --    | B1 b1 t+3
//                          + vmcnt(6)                                + vmcnt(6)
// WAR: every stage issues >=1 barrier after the last ds_read of its slab
//   (A0b0/B0b0 read ph1 -> staged ph2/ph3; B1b0 read ph2 -> ph4; A1b0 read
//   ph3 -> ph5; A0b1/B0b1 read ph5 -> ph6/ph7; B1b1 read ph6 -> ph8; A1b1
//   read ph7 -> next ph1).
// Drain: vmcnt(6) at ph4 leaves {ph2,ph3,ph4} -> prev ph6..8 + ph1 retired,
//   covering consumers ph5(A0,B0 b1), ph6(B1 b1), ph7(A1 b1).  vmcnt(6) at
//   ph8 leaves {ph6,ph7,ph8} -> ph2..ph5 retired, covering next-iter
//   ph1(A0,B0 b0), ph2(B1 b0), ph3(A1 b0). Min issue->drain distance 3 phases.
// Prologue: b0 tile0 {A0,B0,B1,A1} then b1 tile1 {A0,B0,B1}; vmcnt(6)
//   leaves exactly the 3 b1 groups = steady-state invariant. A1 b1 t=1 is
//   staged by ph1 of it=0. Tail: t2/t3 clamped to NT-1, never skipped.
// ---------------------------------------------------------------------------

typedef __bf16 bf16x8 __attribute__((ext_vector_type(8)));
typedef float  f32x4  __attribute__((ext_vector_type(4)));
typedef unsigned short u16x8 __attribute__((ext_vector_type(8)));

#define AS1C(p) ((const __attribute__((address_space(1))) void*)(p))
#define AS3(p)  ((__attribute__((address_space(3))) void*)(p))

__device__ __forceinline__ unsigned short f2bf_rne(float f) {
  unsigned int u = __float_as_uint(f);
  u += 0x7FFFu + ((u >> 16) & 1u);
  return (unsigned short)(u >> 16);
}

constexpr int M_ = 16384;   // 4 * 4096
constexpr int N_ = 2048;    // D_out
constexpr int K_ = 2048;    // D_in
constexpr int R_ = 16;
constexpr float SCALING = 2.0f;  // 32/16

constexpr int BM = 256, BN = 256, BK = 64;
constexpr int NT = K_ / BK;      // 32 k-tiles, 16 loop iterations

// ---- kernel 1: x f32 -> bf16, 8 elems/thread --------------------------------
__global__ __launch_bounds__(256) void cvt_kernel(const float* __restrict__ in,
                                                  unsigned short* __restrict__ out) {
  size_t i = (size_t)blockIdx.x * blockDim.x + threadIdx.x;
  const float4* p = (const float4*)in;
  float4 a = p[2 * i];
  float4 b = p[2 * i + 1];
  u16x8 o;
  o[0] = f2bf_rne(a.x); o[1] = f2bf_rne(a.y); o[2] = f2bf_rne(a.z); o[3] = f2bf_rne(a.w);
  o[4] = f2bf_rne(b.x); o[5] = f2bf_rne(b.y); o[6] = f2bf_rne(b.z); o[7] = f2bf_rne(b.w);
  ((u16x8*)out)[i] = o;
}

// ---- kernel 2: W_eff = bf16(W + 2 * B @ A), [N,K] row-major -----------------
__global__ __launch_bounds__(256) void weff_kernel(const float* __restrict__ W,
                                                   const float* __restrict__ A,
                                                   const float* __restrict__ Bl,
                                                   unsigned short* __restrict__ out) {
  int idx = blockIdx.x * blockDim.x + threadIdx.x;  // over N_*K_
  int o = idx >> 11;        // / 2048
  int d = idx & 2047;       // % 2048
  float acc = W[idx];
#pragma unroll
  for (int r = 0; r < R_; ++r)
    acc = fmaf(SCALING * Bl[o * R_ + r], A[r * K_ + d], acc);
  out[idx] = f2bf_rne(acc);
}

// ---- kernel 3: C[M,N] = Xb[M,K] @ W_eff[N,K]^T  (bf16 in, f32 out) ----------
__global__ __launch_bounds__(512, 2) void gemm_kernel(const unsigned short* __restrict__ X,
                                                      const unsigned short* __restrict__ W,
                                                      float* __restrict__ C) {
  __shared__ __align__(16) unsigned short sA[2][BM * BK];  // 2 x 32 KB
  __shared__ __align__(16) unsigned short sB[2][BN * BK];  // 2 x 32 KB

  const int tid  = threadIdx.x;
  const int w    = tid >> 6;
  const int lane = tid & 63;
  const int fm   = lane & 15;
  const int quad = lane >> 4;

  // XCD-aware swizzle: 512 blocks, 8 XCDs, each XCD gets 8 bm-rows x 8 bn-cols.
  const int id = blockIdx.x;
  const int bm = ((id & 7) * 8 + (id >> 6)) * BM;  // (xcd*8 + slot/8) * 256
  const int bn = ((id >> 3) & 7) * BN;             // (slot%8) * 256

  const int wrow = (w >> 2) * 128;  // wave's row offset in 256-row tile
  const int wcol = (w & 3) * 64;    // wave's col offset

  // --- staging addressing (identical to R4/R5, correctness-proven) ---------
  const int strow = tid >> 3;                  // 0..63
  const int gseg  = ((tid & 7) - strow) & 7;   // (g + row) & 7 LDS seg swizzle
  const int brow0 = 64 * (tid >> 8) + (strow & 31);

  const unsigned short* xa = X + (size_t)(bm + strow) * K_ + gseg * 8;
  const unsigned short* xb = W + (size_t)(bn + brow0) * K_ + gseg * 8;

  const int aw = w * 8 * BK;                               // A wave-uniform base
  const int bw = ((w >> 2) * 64 + (w & 3) * 8) * BK;       // B wave-uniform base

  // fragment k-offsets: phys seg = (g + row)&7, row===fm (mod 8), g = quad/+4
  const int sp0 = ((quad + fm) & 7) * 8;
  const int sp1 = ((quad + fm + 4) & 7) * 8;

  f32x4 acc[8][4] = {};
  bf16x8 af[4][2];        // current hm's A fragments (persist across phases)
  bf16x8 bv0[2][2];       // hn=0 B fragments (persist)
  bf16x8 bv1[2][2];       // hn=1 B fragments (persist)

#define STAGE_A(hm, kt, b) do {                                                   \
    __builtin_amdgcn_global_load_lds(AS1C(xa + (size_t)((hm) * 64) * K_ + (kt) * BK), \
        AS3(&sA[b][((hm) * 64) * BK + aw]), 16, 0, 0);                            \
    __builtin_amdgcn_global_load_lds(AS1C(xa + (size_t)((hm) * 64 + 128) * K_ + (kt) * BK), \
        AS3(&sA[b][((hm) * 64 + 128) * BK + aw]), 16, 0, 0);                      \
  } while (0)

#define STAGE_B(hn, kt, b) do {                                                   \
    __builtin_amdgcn_global_load_lds(AS1C(xb + (size_t)((hn) * 32) * K_ + (kt) * BK), \
        AS3(&sB[b][((hn) * 32) * BK + bw]), 16, 0, 0);                            \
    __builtin_amdgcn_global_load_lds(AS1C(xb + (size_t)((hn) * 32 + 128) * K_ + (kt) * BK), \
        AS3(&sB[b][((hn) * 32 + 128) * BK + bw]), 16, 0, 0);                      \
  } while (0)

#define LOAD_A(hm, tb) do {                                                       \
    _Pragma("unroll")                                                             \
    for (int i2 = 0; i2 < 4; ++i2) {                                              \
      const int ra = (wrow + (hm) * 64 + i2 * 16 + fm) * BK;                      \
      af[i2][0] = *(const bf16x8*)&sA[tb][ra + sp0];                              \
      af[i2][1] = *(const bf16x8*)&sA[tb][ra + sp1];                              \
    }                                                                             \
  } while (0)

#define LOAD_B(bv, hn, tb) do {                                                   \
    _Pragma("unroll")                                                             \
    for (int j2 = 0; j2 < 2; ++j2) {                                              \
      const int rb = (wcol + (hn) * 32 + j2 * 16 + fm) * BK;                      \
      bv[j2][0] = *(const bf16x8*)&sB[tb][rb + sp0];                              \
      bv[j2][1] = *(const bf16x8*)&sB[tb][rb + sp1];                              \
    }                                                                             \
  } while (0)

#define MFMA_Q(hm, hn, bv) do {                                                   \
    __builtin_amdgcn_s_setprio(1);                                                \
    _Pragma("unroll")                                                             \
    for (int ks = 0; ks < 2; ++ks)                                                \
      _Pragma("unroll")                                                           \
      for (int i2 = 0; i2 < 4; ++i2)                                              \
        _Pragma("unroll")                                                         \
        for (int j2 = 0; j2 < 2; ++j2)                                            \
          acc[(hm) * 4 + i2][(hn) * 2 + j2] = __builtin_amdgcn_mfma_f32_16x16x32_bf16( \
              af[i2][ks], (bv)[j2][ks], acc[(hm) * 4 + i2][(hn) * 2 + j2], 0, 0, 0); \
    __builtin_amdgcn_s_setprio(0);                                                \
  } while (0)

#define PH_BAR __builtin_amdgcn_s_barrier()
#define LGKM0  asm volatile("s_waitcnt lgkmcnt(0)" ::: "memory")
#define VMC6   asm volatile("s_waitcnt vmcnt(6)" ::: "memory")

  // prologue: b0 tile0 fully, b1 tile1 {A0,B0,B1}; vmcnt(6) drains the 8 b0
  // loads, leaving the 3 b1 groups -> steady-state invariant.
  STAGE_A(0, 0, 0);
  STAGE_B(0, 0, 0);
  STAGE_B(1, 0, 0);
  STAGE_A(1, 0, 0);
  STAGE_A(0, 1, 1);
  STAGE_B(0, 1, 1);
  STAGE_B(1, 1, 1);
  VMC6;
  PH_BAR;

#pragma unroll 1
  for (int it = 0; it < NT / 2; ++it) {
    const int t1 = 2 * it + 1;                              // always < NT
    const int t2 = (2 * it + 2 < NT) ? 2 * it + 2 : NT - 1; // clamped, never skipped
    const int t3 = (2 * it + 3 < NT) ? 2 * it + 3 : NT - 1;

    // ph1: (0,0) b0 — 12 ds_reads
    LOAD_A(0, 0); LOAD_B(bv0, 0, 0);
    STAGE_A(1, t1, 1);
    PH_BAR; LGKM0; MFMA_Q(0, 0, bv0); PH_BAR;
    // ph2: (0,1) b0 — 4 ds_reads
    LOAD_B(bv1, 1, 0);
    STAGE_A(0, t2, 0);
    PH_BAR; LGKM0; MFMA_Q(0, 1, bv1); PH_BAR;
    // ph3: (1,1) b0 — 8 ds_reads
    LOAD_A(1, 0);
    STAGE_B(0, t2, 0);
    PH_BAR; LGKM0; MFMA_Q(1, 1, bv1); PH_BAR;
    // ph4: (1,0) b0 — 0 ds_reads, counted drain
    STAGE_B(1, t2, 0);
    PH_BAR; MFMA_Q(1, 0, bv0); VMC6; PH_BAR;

    // ph5: (0,0) b1
    LOAD_A(0, 1); LOAD_B(bv0, 0, 1);
    STAGE_A(1, t2, 0);
    PH_BAR; LGKM0; MFMA_Q(0, 0, bv0); PH_BAR;
    // ph6: (0,1) b1
    LOAD_B(bv1, 1, 1);
    STAGE_A(0, t3, 1);
    PH_BAR; LGKM0; MFMA_Q(0, 1, bv1); PH_BAR;
    // ph7: (1,1) b1
    LOAD_A(1, 1);
    STAGE_B(0, t3, 1);
    PH_BAR; LGKM0; MFMA_Q(1, 1, bv1); PH_BAR;
    // ph8: (1,0) b1 — counted drain
    STAGE_B(1, t3, 1);
    PH_BAR; MFMA_Q(1, 0, bv0); VMC6; PH_BAR;
  }

  // drain in-flight LDS-writes before this workgroup's LDS can be reassigned
  asm volatile("s_waitcnt vmcnt(0)" ::: "memory");

  // epilogue: C/D layout col = lane&15, row = (lane>>4)*4 + r. Nontemporal:
  // C is never re-read; keep it out of L2/L3 so X/W stay resident.
  const int r0 = quad * 4;
#pragma unroll
  for (int i = 0; i < 8; ++i) {
#pragma unroll
    for (int j = 0; j < 4; ++j) {
      size_t base = (size_t)(bm + wrow + i * 16 + r0) * N_ + (size_t)(bn + wcol + j * 16 + fm);
#pragma unroll
      for (int r = 0; r < 4; ++r)
        __builtin_nontemporal_store(acc[i][j][r], &C[base + (size_t)r * N_]);
    }
  }
#undef PH_BAR
#undef LGKM0
#undef VMC6
#undef MFMA_Q
#undef LOAD_A
#undef LOAD_B
#undef STAGE_A
#undef STAGE_B
}

extern "C" void kernel_launch(void* const* d_in, const int* in_sizes, int n_in,
                              void* d_out, int out_size, void* d_ws, size_t ws_size,
                              hipStream_t stream) {
  const float* x  = (const float*)d_in[0];  // [4,4096,2048]
  const float* W  = (const float*)d_in[1];  // [2048,2048]
  const float* A  = (const float*)d_in[2];  // [16,2048]
  const float* Bl = (const float*)d_in[3];  // [2048,16]
  float* out = (float*)d_out;               // [4,4096,2048] f32

  // workspace: Xb (M*K bf16 = 64 MB) | W_eff (N*K bf16 = 8 MB)
  unsigned short* Xb   = (unsigned short*)d_ws;
  unsigned short* Weff = Xb + (size_t)M_ * K_;

  cvt_kernel<<<(int)((size_t)M_ * K_ / 8 / 256), 256, 0, stream>>>(x, Xb);
  weff_kernel<<<(N_ * K_) / 256, 256, 0, stream>>>(W, A, Bl, Weff);

  gemm_kernel<<<(M_ / BM) * (N_ / BN), 512, 0, stream>>>(Xb, Weff, out);
}

// Round 5
// 376.182 us; speedup vs baseline: 1.0773x; 1.0099x over previous
//
#include <hip/hip_runtime.h>

// ---------------------------------------------------------------------------
// LoRA forward: out = x @ W^T + 2 * (x @ A^T) @ B^T
// R8: R7's pipelined-read schedule with the COLLECTIVE-DRAIN race fixed.
//   vmcnt is per-wave; slabs are staged by all 8 waves. A read is safe only
//   after (every wave's covering vmcnt) -> barrier. R7 had vmcnt and read in
//   the same inter-barrier region at b4/b8/prologue -> absmax 1.18.
//   R8 moves the counted waits one body earlier (end of b3 / b7, before the
//   barrier) and puts the prologue pre-reads AFTER the prologue barrier.
// Body = { MFMA(P); ds_reads for P+1; stage; [VMC4 @ b3,b7]; barrier }.
// Quadrant snake (0,0)->(0,1)->(1,1)->(1,0); frags in regs: af (one hm),
// bv0+bv1 (both hn). 24 ds_read_b128 / wave / K-tile (minimal).
// Stage map (s_k = stage of body k; iter computes t0=2it in b0, t1 in b1):
//   b1 MFMA(0,0)b0 | rd B1b0      | s1=A1 b1 t1
//   b2 MFMA(0,1)b0 | rd A1b0      | s2=A0 b0 t2
//   b3 MFMA(1,1)b0 |              | s3=B0 b0 t2 | VMC4
//   b4 MFMA(1,0)b0 | rd A0b1,B0b1 | s4=B1 b0 t2
//   b5 MFMA(0,0)b1 | rd B1b1      | s5=A1 b0 t2
//   b6 MFMA(0,1)b1 | rd A1b1      | s6=A0 b1 t3
//   b7 MFMA(1,1)b1 |              | s7=B0 b1 t3 | VMC4
//   b8 MFMA(1,0)b1 | rd A0b0,B0b0 | s8=B1 b1 t3
// Collective drains (2 instr/group, oldest-first; leftover entering b1 =
// {s6p,s7p,s8p} = prologue {A0b1,B0b1,B1b1}):
//   D3 (end b3): outstanding {s6p,s7p,s8p,s1,s2,s3}=12 -> vmcnt(4) retires
//     s6p,s7p,s8p,s1; barrier. Covers b4 rd A0b1(s6p),B0b1(s7p);
//     b5 rd B1b1(s8p); b6 rd A1b1(s1).
//   D7 (end b7): outstanding {s2..s7}=12 -> retires s2,s3,s4,s5; barrier.
//     Covers b8 rd A0b0(s2),B0b0(s3); next b1 rd B1b0(s4); b2 rd A1b0(s5).
//     Leaves {s6,s7}; +s8 at b8 -> invariant restored.
// WAR: every stage issues >=1 barrier after the last read of the slab it
//   overwrites (s1:b6p, s2/s3: prev b8 reads, s4:b1, s5:b2, s6/s7:b4, s8:b5).
// Prologue: b0 tile0 {A0,B0,B1,A1} + b1 tile1 {A0,B0,B1}; VMC6 retires the
//   4 b0 groups; BARRIER (collective); then pre-read A0b0,B0b0.
// Tail: t2/t3 clamped to NT-1; it=15 re-stages tile31 over identical bytes
//   (benign); final b8 reads unused.
// ---------------------------------------------------------------------------

typedef __bf16 bf16x8 __attribute__((ext_vector_type(8)));
typedef float  f32x4  __attribute__((ext_vector_type(4)));
typedef unsigned short u16x8 __attribute__((ext_vector_type(8)));

#define AS1C(p) ((const __attribute__((address_space(1))) void*)(p))
#define AS3(p)  ((__attribute__((address_space(3))) void*)(p))

__device__ __forceinline__ unsigned short f2bf_rne(float f) {
  unsigned int u = __float_as_uint(f);
  u += 0x7FFFu + ((u >> 16) & 1u);
  return (unsigned short)(u >> 16);
}

constexpr int M_ = 16384;   // 4 * 4096
constexpr int N_ = 2048;    // D_out
constexpr int K_ = 2048;    // D_in
constexpr int R_ = 16;
constexpr float SCALING = 2.0f;  // 32/16

constexpr int BM = 256, BN = 256, BK = 64;
constexpr int NT = K_ / BK;      // 32 k-tiles, 16 loop iterations

// ---- kernel 1: x f32 -> bf16, 8 elems/thread --------------------------------
__global__ __launch_bounds__(256) void cvt_kernel(const float* __restrict__ in,
                                                  unsigned short* __restrict__ out) {
  size_t i = (size_t)blockIdx.x * blockDim.x + threadIdx.x;
  const float4* p = (const float4*)in;
  float4 a = p[2 * i];
  float4 b = p[2 * i + 1];
  u16x8 o;
  o[0] = f2bf_rne(a.x); o[1] = f2bf_rne(a.y); o[2] = f2bf_rne(a.z); o[3] = f2bf_rne(a.w);
  o[4] = f2bf_rne(b.x); o[5] = f2bf_rne(b.y); o[6] = f2bf_rne(b.z); o[7] = f2bf_rne(b.w);
  ((u16x8*)out)[i] = o;
}

// ---- kernel 2: W_eff = bf16(W + 2 * B @ A), [N,K] row-major -----------------
__global__ __launch_bounds__(256) void weff_kernel(const float* __restrict__ W,
                                                   const float* __restrict__ A,
                                                   const float* __restrict__ Bl,
                                                   unsigned short* __restrict__ out) {
  int idx = blockIdx.x * blockDim.x + threadIdx.x;  // over N_*K_
  int o = idx >> 11;        // / 2048
  int d = idx & 2047;       // % 2048
  float acc = W[idx];
#pragma unroll
  for (int r = 0; r < R_; ++r)
    acc = fmaf(SCALING * Bl[o * R_ + r], A[r * K_ + d], acc);
  out[idx] = f2bf_rne(acc);
}

// ---- kernel 3: C[M,N] = Xb[M,K] @ W_eff[N,K]^T  (bf16 in, f32 out) ----------
__global__ __launch_bounds__(512, 2) void gemm_kernel(const unsigned short* __restrict__ X,
                                                      const unsigned short* __restrict__ W,
                                                      float* __restrict__ C) {
  __shared__ __align__(16) unsigned short sA[2][BM * BK];  // 2 x 32 KB
  __shared__ __align__(16) unsigned short sB[2][BN * BK];  // 2 x 32 KB

  const int tid  = threadIdx.x;
  const int w    = tid >> 6;
  const int lane = tid & 63;
  const int fm   = lane & 15;
  const int quad = lane >> 4;

  // XCD-aware swizzle: 512 blocks, 8 XCDs, each XCD gets 8 bm-rows x 8 bn-cols.
  const int id = blockIdx.x;
  const int bm = ((id & 7) * 8 + (id >> 6)) * BM;  // (xcd*8 + slot/8) * 256
  const int bn = ((id >> 3) & 7) * BN;             // (slot%8) * 256

  const int wrow = (w >> 2) * 128;  // wave's row offset in 256-row tile
  const int wcol = (w & 3) * 64;    // wave's col offset

  // --- staging addressing (identical to R4-R6, correctness-proven) ---------
  const int strow = tid >> 3;                  // 0..63
  const int gseg  = ((tid & 7) - strow) & 7;   // (g + row) & 7 LDS seg swizzle
  const int brow0 = 64 * (tid >> 8) + (strow & 31);

  const unsigned short* xa = X + (size_t)(bm + strow) * K_ + gseg * 8;
  const unsigned short* xb = W + (size_t)(bn + brow0) * K_ + gseg * 8;

  const int aw = w * 8 * BK;                               // A wave-uniform base
  const int bw = ((w >> 2) * 64 + (w & 3) * 8) * BK;       // B wave-uniform base

  // fragment k-offsets: phys seg = (g + row)&7, row===fm (mod 8), g = quad/+4
  const int sp0 = ((quad + fm) & 7) * 8;
  const int sp1 = ((quad + fm + 4) & 7) * 8;

  f32x4 acc[8][4] = {};
  bf16x8 af[4][2];        // current hm's A fragments (persist across bodies)
  bf16x8 bv0[2][2];       // hn=0 B fragments (persist)
  bf16x8 bv1[2][2];       // hn=1 B fragments (persist)

#define STAGE_A(hm, kt, b) do {                                                   \
    __builtin_amdgcn_global_load_lds(AS1C(xa + (size_t)((hm) * 64) * K_ + (kt) * BK), \
        AS3(&sA[b][((hm) * 64) * BK + aw]), 16, 0, 0);                            \
    __builtin_amdgcn_global_load_lds(AS1C(xa + (size_t)((hm) * 64 + 128) * K_ + (kt) * BK), \
        AS3(&sA[b][((hm) * 64 + 128) * BK + aw]), 16, 0, 0);                      \
  } while (0)

#define STAGE_B(hn, kt, b) do {                                                   \
    __builtin_amdgcn_global_load_lds(AS1C(xb + (size_t)((hn) * 32) * K_ + (kt) * BK), \
        AS3(&sB[b][((hn) * 32) * BK + bw]), 16, 0, 0);                            \
    __builtin_amdgcn_global_load_lds(AS1C(xb + (size_t)((hn) * 32 + 128) * K_ + (kt) * BK), \
        AS3(&sB[b][((hn) * 32 + 128) * BK + bw]), 16, 0, 0);                      \
  } while (0)

#define LOAD_A(hm, tb) do {                                                       \
    _Pragma("unroll")                                                             \
    for (int i2 = 0; i2 < 4; ++i2) {                                              \
      const int ra = (wrow + (hm) * 64 + i2 * 16 + fm) * BK;                      \
      af[i2][0] = *(const bf16x8*)&sA[tb][ra + sp0];                              \
      af[i2][1] = *(const bf16x8*)&sA[tb][ra + sp1];                              \
    }                                                                             \
  } while (0)

#define LOAD_B(bv, hn, tb) do {                                                   \
    _Pragma("unroll")                                                             \
    for (int j2 = 0; j2 < 2; ++j2) {                                              \
      const int rb = (wcol + (hn) * 32 + j2 * 16 + fm) * BK;                      \
      bv[j2][0] = *(const bf16x8*)&sB[tb][rb + sp0];                              \
      bv[j2][1] = *(const bf16x8*)&sB[tb][rb + sp1];                              \
    }                                                                             \
  } while (0)

  // No asm lgkmcnt: compiler inserts fine-grained lgkm waits for the
  // ds_read->MFMA register deps (reads were issued one body earlier).
#define MFMA_Q(hm, hn, bv) do {                                                   \
    __builtin_amdgcn_s_setprio(1);                                                \
    _Pragma("unroll")                                                             \
    for (int ks = 0; ks < 2; ++ks)                                                \
      _Pragma("unroll")                                                           \
      for (int i2 = 0; i2 < 4; ++i2)                                              \
        _Pragma("unroll")                                                         \
        for (int j2 = 0; j2 < 2; ++j2)                                            \
          acc[(hm) * 4 + i2][(hn) * 2 + j2] = __builtin_amdgcn_mfma_f32_16x16x32_bf16( \
              af[i2][ks], (bv)[j2][ks], acc[(hm) * 4 + i2][(hn) * 2 + j2], 0, 0, 0); \
    __builtin_amdgcn_s_setprio(0);                                                \
  } while (0)

#define PH_BAR __builtin_amdgcn_s_barrier()
#define VMC4   asm volatile("s_waitcnt vmcnt(4)" ::: "memory")
#define VMC6   asm volatile("s_waitcnt vmcnt(6)" ::: "memory")

  // prologue: b0 tile0 fully, b1 tile1 {A0,B0,B1}; VMC6 retires the 4 b0
  // groups; BARRIER makes the drain collective; then pre-read body1's
  // operands (safe: slabs collectively drained).
  STAGE_A(0, 0, 0);
  STAGE_B(0, 0, 0);
  STAGE_B(1, 0, 0);
  STAGE_A(1, 0, 0);
  STAGE_A(0, 1, 1);
  STAGE_B(0, 1, 1);
  STAGE_B(1, 1, 1);
  VMC6;
  PH_BAR;
  LOAD_A(0, 0); LOAD_B(bv0, 0, 0);

#pragma unroll 1
  for (int it = 0; it < NT / 2; ++it) {
    const int t1 = 2 * it + 1;                              // always < NT
    const int t2 = (2 * it + 2 < NT) ? 2 * it + 2 : NT - 1; // clamped, never skipped
    const int t3 = (2 * it + 3 < NT) ? 2 * it + 3 : NT - 1;

    // body1: MFMA (0,0) b0 | rd B1 b0 | s1 = A1 b1 t1
    MFMA_Q(0, 0, bv0);
    LOAD_B(bv1, 1, 0);
    STAGE_A(1, t1, 1);
    PH_BAR;
    // body2: MFMA (0,1) b0 | rd A1 b0 | s2 = A0 b0 t2
    MFMA_Q(0, 1, bv1);
    LOAD_A(1, 0);
    STAGE_A(0, t2, 0);
    PH_BAR;
    // body3: MFMA (1,1) b0 | s3 = B0 b0 t2 | VMC4 (collective via barrier)
    MFMA_Q(1, 1, bv1);
    STAGE_B(0, t2, 0);
    VMC4;
    PH_BAR;
    // body4: MFMA (1,0) b0 | rd A0,B0 b1 (drained @D3) | s4 = B1 b0 t2
    MFMA_Q(1, 0, bv0);
    LOAD_A(0, 1); LOAD_B(bv0, 0, 1);
    STAGE_B(1, t2, 0);
    PH_BAR;

    // body5: MFMA (0,0) b1 | rd B1 b1 (D3) | s5 = A1 b0 t2
    MFMA_Q(0, 0, bv0);
    LOAD_B(bv1, 1, 1);
    STAGE_A(1, t2, 0);
    PH_BAR;
    // body6: MFMA (0,1) b1 | rd A1 b1 (D3) | s6 = A0 b1 t3
    MFMA_Q(0, 1, bv1);
    LOAD_A(1, 1);
    STAGE_A(0, t3, 1);
    PH_BAR;
    // body7: MFMA (1,1) b1 | s7 = B0 b1 t3 | VMC4
    MFMA_Q(1, 1, bv1);
    STAGE_B(0, t3, 1);
    VMC4;
    PH_BAR;
    // body8: MFMA (1,0) b1 | rd A0,B0 b0 (D7) | s8 = B1 b1 t3
    MFMA_Q(1, 0, bv0);
    LOAD_A(0, 0); LOAD_B(bv0, 0, 0);
    STAGE_B(1, t3, 1);
    PH_BAR;
  }

  // drain in-flight LDS-writes before this workgroup's LDS can be reassigned
  asm volatile("s_waitcnt vmcnt(0)" ::: "memory");

  // epilogue: C/D layout col = lane&15, row = (lane>>4)*4 + r. Nontemporal:
  // C is never re-read; keep it out of L2/L3 so X/W stay resident.
  const int r0 = quad * 4;
#pragma unroll
  for (int i = 0; i < 8; ++i) {
#pragma unroll
    for (int j = 0; j < 4; ++j) {
      size_t base = (size_t)(bm + wrow + i * 16 + r0) * N_ + (size_t)(bn + wcol + j * 16 + fm);
#pragma unroll
      for (int r = 0; r < 4; ++r)
        __builtin_nontemporal_store(acc[i][j][r], &C[base + (size_t)r * N_]);
    }
  }
#undef PH_BAR
#undef VMC4
#undef VMC6
#undef MFMA_Q
#undef LOAD_A
#undef LOAD_B
#undef STAGE_A
#undef STAGE_B
}

extern "C" void kernel_launch(void* const* d_in, const int* in_sizes, int n_in,
                              void* d_out, int out_size, void* d_ws, size_t ws_size,
                              hipStream_t stream) {
  const float* x  = (const float*)d_in[0];  // [4,4096,2048]
  const float* W  = (const float*)d_in[1];  // [2048,2048]
  const float* A  = (const float*)d_in[2];  // [16,2048]
  const float* Bl = (const float*)d_in[3];  // [2048,16]
  float* out = (float*)d_out;               // [4,4096,2048] f32

  // workspace: Xb (M*K bf16 = 64 MB) | W_eff (N*K bf16 = 8 MB)
  unsigned short* Xb   = (unsigned short*)d_ws;
  unsigned short* Weff = Xb + (size_t)M_ * K_;

  cvt_kernel<<<(int)((size_t)M_ * K_ / 8 / 256), 256, 0, stream>>>(x, Xb);
  weff_kernel<<<(N_ * K_) / 256, 256, 0, stream>>>(W, A, Bl, Weff);

  gemm_kernel<<<(M_ / BM) * (N_ / BN), 512, 0, stream>>>(Xb, Weff, out);
}